// Round 11
// baseline (137.104 us; speedup 1.0000x reference)
//
#include <hip/hip_runtime.h>
#include <hip/hip_bf16.h>

// MultiLatentAttention on MI355X.
// causal mask t<=l with L=64 => attention only over first 64 tokens.
// out[b] = softmax_groups(x@Wg) @ M[b],  M built from attn_out and Wp (MFMA).
// This round: xb eliminated — gates GEMM consumes fp32 x directly via
// {gll16 fp32 -> LDS convert -> bf16 MFMA} triple pipeline; prep = transposes only.

typedef __attribute__((ext_vector_type(8))) short bf16x8;
typedef __attribute__((ext_vector_type(4))) float f32x4;
typedef __attribute__((ext_vector_type(4))) unsigned short us4;
typedef __attribute__((ext_vector_type(8))) unsigned short us8;

__device__ __forceinline__ void gll16(const void* g, void* l) {
  __builtin_amdgcn_global_load_lds((const __attribute__((address_space(1))) void*)g,
                                   (__attribute__((address_space(3))) void*)l, 16, 0, 0);
}

// ---------------- prep4: 4 weight transposes fp32->bf16 ----------------
__global__ __launch_bounds__(256)
void prep4(const float* __restrict__ Wg, const float* __restrict__ Wk,
           const float* __restrict__ Wv, const float* __restrict__ Wp,
           __hip_bfloat16* __restrict__ WgT, __hip_bfloat16* __restrict__ WkT,
           __hip_bfloat16* __restrict__ WvT, __hip_bfloat16* __restrict__ WpT) {
  const int bid = blockIdx.x, tid = threadIdx.x;
  const int z = bid >> 10, rem = bid & 1023;
  const float* W = (z == 0) ? Wg : ((z == 1) ? Wk : ((z == 2) ? Wv : Wp));
  __hip_bfloat16* Wt = (z == 0) ? WgT : ((z == 1) ? WkT : ((z == 2) ? WvT : WpT));
  __shared__ float tile[32][33];
  const int bx = (rem & 31) * 32, by = (rem >> 5) * 32;
  const int tx = tid & 31, ty = tid >> 5;  // 32x8
  #pragma unroll
  for (int j = 0; j < 32; j += 8)
    tile[ty + j][tx] = W[(size_t)(by + ty + j) * 1024 + bx + tx];
  __syncthreads();
  #pragma unroll
  for (int j = 0; j < 32; j += 8)
    Wt[(size_t)(bx + ty + j) * 1024 + by + tx] = __float2bfloat16(tile[tx][ty + j]);
}

// ---------------- gates GEMM from fp32 x: 256x256, BK=32, triple pipeline ----------------
// LDS (128KiB): SF[2] fp32 A-tiles (2x32K), SA16[2] bf16 A (2x16K), SB[2] bf16 B (2x16K).
// Iter t: {stage F(t+2)->F[t&1], stage B(t+1)->B[(t+1)&1], convert F[(t+1)&1]->A16[(t+1)&1]}
//         MFMA step t on (A16[t&1], B[t&1]); __syncthreads (drains vmcnt+lgkm).
// All hand-offs barrier-separated: F(t+1) landed via barrier(t-1); A16[(t+1)&1] last read
// at MFMA(t-1); B[(t+1)&1] last read at MFMA(t-1); F[t&1] consumed by convert(t-1).
// bf16 tiles use the PROVEN 8-slot swizzle via paired rows ([256][32] as [128][64]):
// logical (row,s4) at linear chunk (row>>1)*8 + (((row&1)*4+s4) ^ ((row>>1)&7)).
// SF rows are 128B native: physical chunk p holds logical p^(row&7).
// Epilogue: per-64-column-group softmax, bf16 store.
__global__ __launch_bounds__(512)
void gemm_gates_f32(const float* __restrict__ X, const __hip_bfloat16* __restrict__ Bt,
                    __hip_bfloat16* __restrict__ G) {
  __shared__ __align__(16) float SF[2][256 * 32];
  __shared__ __align__(16) unsigned short SA16[2][256 * 32];
  __shared__ __align__(16) unsigned short SB[2][256 * 32];
  const int tid = threadIdx.x;
  const int lane = tid & 63;
  const int w = tid >> 6;            // wave 0..7
  const int wm = w >> 2, wn = w & 3; // 2x4 wave grid; per-wave out 128x64
  const int lr = lane & 15, lk = lane >> 4;
  const int m0 = blockIdx.x * 256, n0 = blockIdx.y * 256;
  const int K = 1024;

  f32x4 acc[8][4] = {};

  auto stageF = [&](int bsel, int kt) {
    #pragma unroll
    for (int r = 0; r < 4; ++r) {
      int c = r * 512 + tid;          // physical fp32 chunk 0..2047 (4 floats)
      int row = c >> 3, p = c & 7;
      int gs = p ^ (row & 7);         // logical slot staged into physical p
      gll16(X + (size_t)(m0 + row) * K + kt + gs * 4, (char*)&SF[bsel][0] + c * 16);
    }
  };
  auto stageB = [&](int bsel, int kt) {
    #pragma unroll
    for (int r = 0; r < 2; ++r) {
      int c = r * 512 + tid;          // physical bf16 chunk 0..1023 (8 bf16)
      int row2 = c >> 3, p = c & 7;
      int l = p ^ (row2 & 7);         // logical slot in row-pair: row=2*row2+(l>>2), s4=l&3
      int row = row2 * 2 + (l >> 2);
      int s4 = l & 3;
      gll16(Bt + (size_t)(n0 + row) * K + kt + s4 * 8, (char*)&SB[bsel][0] + c * 16);
    }
  };
  auto convert = [&](int bsel) {
    #pragma unroll
    for (int r = 0; r < 2; ++r) {
      int c = r * 512 + tid;          // physical bf16 chunk to produce
      int row2 = c >> 3, p = c & 7;
      int l = p ^ (row2 & 7);
      int row = row2 * 2 + (l >> 2);
      int s4 = l & 3;
      int f0 = (2 * s4) ^ (row & 7);      // physical fp32 chunks holding logical 2s4, 2s4+1
      int f1 = (2 * s4 + 1) ^ (row & 7);
      float4 a  = *(const float4*)&SF[bsel][row * 32 + f0 * 4];
      float4 b2 = *(const float4*)&SF[bsel][row * 32 + f1 * 4];
      union { __hip_bfloat16 h[8]; bf16x8 v; } pk;
      pk.h[0] = __float2bfloat16(a.x);  pk.h[1] = __float2bfloat16(a.y);
      pk.h[2] = __float2bfloat16(a.z);  pk.h[3] = __float2bfloat16(a.w);
      pk.h[4] = __float2bfloat16(b2.x); pk.h[5] = __float2bfloat16(b2.y);
      pk.h[6] = __float2bfloat16(b2.z); pk.h[7] = __float2bfloat16(b2.w);
      *(bf16x8*)&SA16[bsel][c * 8] = pk.v;  // physical-linear write
    }
  };

  // prologue
  stageF(0, 0);
  stageB(0, 0);
  __syncthreads();          // F(0), B(0) landed
  convert(0);               // A16[0] ready (after next barrier)
  stageF(1, 32);
  __syncthreads();          // F(1) landed; convert's ds_writes visible

  const int NT = 32;
  for (int t = 0; t < NT; ++t) {
    if (t + 2 < NT) stageF(t & 1, (t + 2) * 32);
    if (t + 1 < NT) {
      stageB((t + 1) & 1, (t + 1) * 32);
      convert((t + 1) & 1);
    }

    const int buf = t & 1;
    bf16x8 bfr[4];
    #pragma unroll
    for (int ni = 0; ni < 4; ++ni) {
      int row = wn * 64 + ni * 16 + lr;
      int ch = ((row >> 1) * 8) + ((((row & 1) << 2) | lk) ^ ((row >> 1) & 7));
      bfr[ni] = *(const bf16x8*)&SB[buf][ch * 8];
    }
    #pragma unroll
    for (int mi = 0; mi < 8; ++mi) {
      int row = wm * 128 + mi * 16 + lr;
      int ch = ((row >> 1) * 8) + ((((row & 1) << 2) | lk) ^ ((row >> 1) & 7));
      bf16x8 a = *(const bf16x8*)&SA16[buf][ch * 8];
      #pragma unroll
      for (int ni = 0; ni < 4; ++ni)
        acc[mi][ni] = __builtin_amdgcn_mfma_f32_16x16x32_bf16(a, bfr[ni], acc[mi][ni], 0, 0, 0);
    }
    __syncthreads();
  }

  // Each wave's 64 columns = one softmax group (head h, l=0..63).
  #pragma unroll
  for (int mi = 0; mi < 8; ++mi) {
    #pragma unroll
    for (int jj = 0; jj < 4; ++jj) {
      float mx = -3.0e38f;
      #pragma unroll
      for (int ni = 0; ni < 4; ++ni) mx = fmaxf(mx, acc[mi][ni][jj]);
      mx = fmaxf(mx, __shfl_xor(mx, 1));
      mx = fmaxf(mx, __shfl_xor(mx, 2));
      mx = fmaxf(mx, __shfl_xor(mx, 4));
      mx = fmaxf(mx, __shfl_xor(mx, 8));
      float e[4];
      float s = 0.f;
      #pragma unroll
      for (int ni = 0; ni < 4; ++ni) { e[ni] = __expf(acc[mi][ni][jj] - mx); s += e[ni]; }
      s += __shfl_xor(s, 1);
      s += __shfl_xor(s, 2);
      s += __shfl_xor(s, 4);
      s += __shfl_xor(s, 8);
      float inv = 1.0f / s;
      int r = m0 + wm * 128 + mi * 16 + lk * 4 + jj;
      #pragma unroll
      for (int ni = 0; ni < 4; ++ni)
        G[(size_t)r * 1024 + n0 + wn * 64 + ni * 16 + lr] = __float2bfloat16(e[ni] * inv);
    }
  }
}

// ---------------- 256x256 2-phase pipelined bf16 GEMM (proven ~49us) — out projection --------
__global__ __launch_bounds__(512, 2)
void gemm256o(const __hip_bfloat16* __restrict__ A, const __hip_bfloat16* __restrict__ Bt,
              float* __restrict__ Cv, int K, int ldc,
              long long astride, long long bstride, long long cstride) {
  __shared__ __align__(16) unsigned short SA[2][256 * 64];
  __shared__ __align__(16) unsigned short SB[2][256 * 64];
  const int tid = threadIdx.x;
  const int lane = tid & 63;
  const int w = tid >> 6;
  const int wm = w >> 2, wn = w & 3;
  const int lr = lane & 15, lk = lane >> 4;
  const int m0 = blockIdx.x * 256, n0 = blockIdx.y * 256;
  const long long b = blockIdx.z;
  const __hip_bfloat16* Ab = A + b * astride;
  const __hip_bfloat16* Bb = Bt + b * bstride;

  f32x4 acc[8][4] = {};

  const int NT = K >> 6;
  int buf = 0;

  auto STAGE = [&](int bsel, int kt) {
    #pragma unroll
    for (int r = 0; r < 4; ++r) {
      int c = r * 512 + tid;
      int row = c >> 3, slot = c & 7;
      int gch = slot ^ (row & 7);
      gll16(Ab + (size_t)(m0 + row) * K + kt + gch * 8, (char*)&SA[bsel][0] + c * 16);
      gll16(Bb + (size_t)(n0 + row) * K + kt + gch * 8, (char*)&SB[bsel][0] + c * 16);
    }
  };

  STAGE(0, 0);
  __syncthreads();

  for (int t = 0; t < NT; ++t) {
    if (t + 1 < NT) STAGE(buf ^ 1, (t + 1) << 6);

    bf16x8 bfr[2][4];
    #pragma unroll
    for (int kk = 0; kk < 2; ++kk)
      #pragma unroll
      for (int ni = 0; ni < 4; ++ni) {
        int row = wn * 64 + ni * 16 + lr;
        int ch = (kk * 4 + lk) ^ (row & 7);
        bfr[kk][ni] = *(const bf16x8*)&SB[buf][row * 64 + ch * 8];
      }
    #pragma unroll
    for (int mi = 0; mi < 8; ++mi) {
      int row = wm * 128 + mi * 16 + lr;
      int ch0 = lk ^ (row & 7);
      int ch1 = (4 + lk) ^ (row & 7);
      bf16x8 a0 = *(const bf16x8*)&SA[buf][row * 64 + ch0 * 8];
      bf16x8 a1 = *(const bf16x8*)&SA[buf][row * 64 + ch1 * 8];
      #pragma unroll
      for (int ni = 0; ni < 4; ++ni)
        acc[mi][ni] = __builtin_amdgcn_mfma_f32_16x16x32_bf16(a0, bfr[0][ni], acc[mi][ni], 0, 0, 0);
      #pragma unroll
      for (int ni = 0; ni < 4; ++ni)
        acc[mi][ni] = __builtin_amdgcn_mfma_f32_16x16x32_bf16(a1, bfr[1][ni], acc[mi][ni], 0, 0, 0);
    }
    __syncthreads();
    buf ^= 1;
  }

  float* C = Cv + b * cstride;
  #pragma unroll
  for (int mi = 0; mi < 8; ++mi) {
    int r = m0 + wm * 128 + mi * 16 + lk * 4;
    #pragma unroll
    for (int ni = 0; ni < 4; ++ni) {
      int c = n0 + wn * 64 + ni * 16 + lr;
      #pragma unroll
      for (int jj = 0; jj < 4; ++jj)
        C[(size_t)(r + jj) * ldc + c] = acc[mi][ni][jj];
    }
  }
}

// ---------------- kv projection from fp32 x, split-K=8: kvp[ks][256][2048] fp32 --------------
// Stacked rows (b*64+t, t<64). 128x128 tile, BK=32, 4 waves, 4 K-iters/block, grid (2,16,8).
// A reg-staged fp32->bf16 (tiny: 1MB total), B gll16 from WkvT.
__global__ __launch_bounds__(256)
void gemm_kv(const float* __restrict__ X, const __hip_bfloat16* __restrict__ Bt,
             float* __restrict__ kvp) {
  __shared__ __align__(16) unsigned short As[128 * 32];
  __shared__ __align__(16) unsigned short Bs[128 * 32];
  const int tid = threadIdx.x;
  const int lane = tid & 63;
  const int w = tid >> 6;
  const int wm = w >> 1, wn = w & 1;
  const int lr = lane & 15, lk = lane >> 4;
  const int m0 = blockIdx.x * 128, n0 = blockIdx.y * 128;
  const int ks = blockIdx.z;
  const int K = 1024;

  f32x4 acc[4][4] = {};

  auto xrow = [&](int rg) { return (size_t)(rg >> 6) * 4096 + (rg & 63); };

  for (int ki = 0; ki < 4; ++ki) {
    int kt = ks * 128 + ki * 32;
    __syncthreads();  // readers done (write-after-read)
    float4 av[4];
    #pragma unroll
    for (int r = 0; r < 2; ++r) {
      int c = r * 256 + tid;          // chunk: row=c>>2, slot=c&3 (plain layout)
      int row = c >> 2, s = c & 3;
      const float* src = X + xrow(m0 + row) * K + kt + s * 8;
      av[2 * r]     = *(const float4*)src;
      av[2 * r + 1] = *(const float4*)(src + 4);
    }
    #pragma unroll
    for (int r = 0; r < 2; ++r) {
      int c = r * 256 + tid;
      int row = c >> 2, s = c & 3;
      gll16(Bt + (size_t)(n0 + row) * K + kt + s * 8, (char*)Bs + c * 16);
    }
    #pragma unroll
    for (int r = 0; r < 2; ++r) {
      int c = r * 256 + tid;
      union { __hip_bfloat16 h[8]; bf16x8 v; } p;
      const float* f = (const float*)&av[2 * r];
      #pragma unroll
      for (int e = 0; e < 8; ++e) p.h[e] = __float2bfloat16(f[e]);
      *(bf16x8*)((char*)As + c * 16) = p.v;
    }
    __syncthreads();  // drains B gll16 + A ds_writes

    bf16x8 af[4], bf[4];
    #pragma unroll
    for (int mi = 0; mi < 4; ++mi)
      af[mi] = *(const bf16x8*)&As[(wm * 64 + mi * 16 + lr) * 32 + lk * 8];
    #pragma unroll
    for (int ni = 0; ni < 4; ++ni)
      bf[ni] = *(const bf16x8*)&Bs[(wn * 64 + ni * 16 + lr) * 32 + lk * 8];
    #pragma unroll
    for (int mi = 0; mi < 4; ++mi)
      #pragma unroll
      for (int ni = 0; ni < 4; ++ni)
        acc[mi][ni] = __builtin_amdgcn_mfma_f32_16x16x32_bf16(af[mi], bf[ni], acc[mi][ni], 0, 0, 0);
  }

  float* C = kvp + (size_t)ks * 256 * 2048;
  #pragma unroll
  for (int mi = 0; mi < 4; ++mi) {
    int r = m0 + wm * 64 + mi * 16 + lk * 4;
    #pragma unroll
    for (int ni = 0; ni < 4; ++ni) {
      int c = n0 + wn * 64 + ni * 16 + lr;
      #pragma unroll
      for (int jj = 0; jj < 4; ++jj)
        C[(size_t)(r + jj) * 2048 + c] = acc[mi][ni][jj];
    }
  }
}

// ---------------- attn (split-K sum + RoPE fused): grid (h=16, b=4), ao out bf16 ------------
__global__ __launch_bounds__(256)
void attn_kernel(const float* __restrict__ kvp, const float* __restrict__ lq,
                 __hip_bfloat16* __restrict__ aoB) {
  const int h = blockIdx.x, b = blockIdx.y;
  __shared__ float Ks[64][64];
  __shared__ float Vs[64][64];
  __shared__ float S[64][65];   // S[l][t]
  __shared__ float Pt[64][65];  // Pt[t][l]
  const int tid = threadIdx.x;

  {
    int r = tid >> 4;            // 0..15
    int c4 = (tid & 15) * 4;     // head-dim col (pairs i0=c4/2, i0+1)
    int i0 = c4 >> 1;
    float inv0 = exp2f(-13.287712379549449f * ((float)i0 * (1.0f / 32.0f)));
    float inv1 = exp2f(-13.287712379549449f * ((float)(i0 + 1) * (1.0f / 32.0f)));
    #pragma unroll
    for (int j = 0; j < 4; ++j) {
      int row = j * 16 + r;      // t
      float4 kf = make_float4(0.f, 0.f, 0.f, 0.f);
      float4 vf = make_float4(0.f, 0.f, 0.f, 0.f);
      #pragma unroll
      for (int ks = 0; ks < 8; ++ks) {
        const float* base = kvp + ((size_t)ks * 256 + b * 64 + row) * 2048 + h * 64;
        float4 kp = *(const float4*)(base + c4);
        float4 vp = *(const float4*)(base + 1024 + c4);
        kf.x += kp.x; kf.y += kp.y; kf.z += kp.z; kf.w += kp.w;
        vf.x += vp.x; vf.y += vp.y; vf.z += vp.z; vf.w += vp.w;
      }
      float a0 = (float)row * inv0, a1 = (float)row * inv1;
      float s0 = sinf(a0), c0 = cosf(a0), s1 = sinf(a1), c1 = cosf(a1);
      *(float4*)&Ks[row][c4] = make_float4(kf.x * c0 - kf.y * s0, kf.x * s0 + kf.y * c0,
                                           kf.z * c1 - kf.w * s1, kf.z * s1 + kf.w * c1);
      *(float4*)&Vs[row][c4] = vf;
    }
  }
  __syncthreads();

  {
    const int w = tid >> 6, l = tid & 63;
    float q[64];
    const float4* lq4 = (const float4*)(lq + ((size_t)l * 16 + h) * 64);
    #pragma unroll
    for (int i = 0; i < 16; ++i) {
      float4 f = lq4[i];
      q[4 * i] = f.x; q[4 * i + 1] = f.y; q[4 * i + 2] = f.z; q[4 * i + 3] = f.w;
    }
    #pragma unroll
    for (int tl = 0; tl < 16; ++tl) {
      int t = w * 16 + tl;
      float a = 0.f;
      #pragma unroll
      for (int d4 = 0; d4 < 16; ++d4) {
        float4 kf = *(const float4*)&Ks[t][d4 * 4];
        a += q[4 * d4] * kf.x + q[4 * d4 + 1] * kf.y + q[4 * d4 + 2] * kf.z + q[4 * d4 + 3] * kf.w;
      }
      S[l][t] = a * 0.125f;
    }
  }
  __syncthreads();

  {
    const int l = tid >> 2, c = tid & 3;
    float sv[16];
    float mx = -3.0e38f;
    #pragma unroll
    for (int i = 0; i < 16; ++i) {
      int t = c * 16 + i;
      sv[i] = S[l][t];
      if (t <= l) mx = fmaxf(mx, sv[i]);
    }
    mx = fmaxf(mx, __shfl_xor(mx, 1));
    mx = fmaxf(mx, __shfl_xor(mx, 2));
    float sum = 0.f;
    float e[16];
    #pragma unroll
    for (int i = 0; i < 16; ++i) {
      int t = c * 16 + i;
      e[i] = (t <= l) ? __expf(sv[i] - mx) : 0.f;
      sum += e[i];
    }
    sum += __shfl_xor(sum, 1);
    sum += __shfl_xor(sum, 2);
    float inv = 1.0f / sum;
    #pragma unroll
    for (int i = 0; i < 16; ++i) Pt[c * 16 + i][l] = e[i] * inv;
  }
  __syncthreads();

  {
    const int w = tid >> 6, l = tid & 63;
    float o[16];
    #pragma unroll
    for (int i = 0; i < 16; ++i) o[i] = 0.f;
    for (int t = 0; t < 64; ++t) {
      float p = Pt[t][l];
      #pragma unroll
      for (int d4 = 0; d4 < 4; ++d4) {
        float4 vf = *(const float4*)&Vs[t][w * 16 + d4 * 4];
        o[4 * d4]     += p * vf.x;
        o[4 * d4 + 1] += p * vf.y;
        o[4 * d4 + 2] += p * vf.z;
        o[4 * d4 + 3] += p * vf.w;
      }
    }
    union { __hip_bfloat16 h[16]; us8 v[2]; } u;
    #pragma unroll
    for (int i = 0; i < 16; ++i) u.h[i] = __float2bfloat16(o[i]);
    us8* dst = (us8*)(aoB + (((size_t)b * 16 + h) * 64 + l) * 64 + w * 16);
    dst[0] = u.v[0];
    dst[1] = u.v[1];
  }
}

// ---------------- Mt build via MFMA: Mt_slice[256c][64l] = WpT_slice[256c][64d] @ ao^T --------
__global__ __launch_bounds__(256)
void build_mt_mfma(const __hip_bfloat16* __restrict__ aoB, const __hip_bfloat16* __restrict__ WpT,
                   __hip_bfloat16* __restrict__ Mt) {
  __shared__ __align__(16) unsigned short SW[256 * 64];
  __shared__ __align__(16) unsigned short SAo[64 * 64];
  const int ct = blockIdx.x, h = blockIdx.y, b = blockIdx.z;
  const int tid = threadIdx.x;
  const int lane = tid & 63;
  const int w = tid >> 6;            // wave 0..3, c-range w*64..w*64+63
  const int lr = lane & 15, lk = lane >> 4;

  #pragma unroll
  for (int j = 0; j < 8; ++j) {
    int c2 = j * 256 + tid;
    int row = c2 >> 3, slot = c2 & 7;
    int gch = slot ^ (row & 7);
    gll16(WpT + (size_t)(ct * 256 + row) * 1024 + h * 64 + gch * 8, (char*)SW + c2 * 16);
  }
  const __hip_bfloat16* aob = aoB + (((size_t)b * 16 + h) * 64) * 64;
  #pragma unroll
  for (int j = 0; j < 2; ++j) {
    int c2 = j * 256 + tid;
    int row = c2 >> 3, slot = c2 & 7;
    int gch = slot ^ (row & 7);
    gll16(aob + (size_t)row * 64 + gch * 8, (char*)SAo + c2 * 16);
  }
  __syncthreads();

  f32x4 acc[4][4] = {};
  bf16x8 bfr[2][4];
  #pragma unroll
  for (int kk = 0; kk < 2; ++kk)
    #pragma unroll
    for (int ni = 0; ni < 4; ++ni) {
      int row = ni * 16 + lr;
      int ch = (kk * 4 + lk) ^ (row & 7);
      bfr[kk][ni] = *(const bf16x8*)&SAo[row * 64 + ch * 8];
    }
  #pragma unroll
  for (int mi = 0; mi < 4; ++mi) {
    int row = w * 64 + mi * 16 + lr;
    int ch0 = lk ^ (row & 7);
    int ch1 = (4 + lk) ^ (row & 7);
    bf16x8 a0 = *(const bf16x8*)&SW[row * 64 + ch0 * 8];
    bf16x8 a1 = *(const bf16x8*)&SW[row * 64 + ch1 * 8];
    #pragma unroll
    for (int ni = 0; ni < 4; ++ni)
      acc[mi][ni] = __builtin_amdgcn_mfma_f32_16x16x32_bf16(a0, bfr[0][ni], acc[mi][ni], 0, 0, 0);
    #pragma unroll
    for (int ni = 0; ni < 4; ++ni)
      acc[mi][ni] = __builtin_amdgcn_mfma_f32_16x16x32_bf16(a1, bfr[1][ni], acc[mi][ni], 0, 0, 0);
  }

  #pragma unroll
  for (int mi = 0; mi < 4; ++mi) {
    int c = ct * 256 + w * 64 + mi * 16 + lk * 4;
    #pragma unroll
    for (int ni = 0; ni < 4; ++ni) {
      int l = ni * 16 + lr;
      #pragma unroll
      for (int jj = 0; jj < 4; ++jj)
        Mt[((size_t)b * 1024 + c + jj) * 1024 + h * 64 + l] = __float2bfloat16(acc[mi][ni][jj]);
    }
  }
}

extern "C" void kernel_launch(void* const* d_in, const int* in_sizes, int n_in,
                              void* d_out, int out_size, void* d_ws, size_t ws_size,
                              hipStream_t stream) {
  const float* x  = (const float*)d_in[0];
  const float* lq = (const float*)d_in[1];
  const float* Wk = (const float*)d_in[2];
  const float* Wv = (const float*)d_in[3];
  const float* Wg = (const float*)d_in[4];
  const float* Wp = (const float*)d_in[5];
  float* out = (float*)d_out;

  // workspace layout (bytes) — xb eliminated
  char* w = (char*)d_ws;
  __hip_bfloat16* G    = (__hip_bfloat16*)(w);              // 33,554,432
  __hip_bfloat16* WgT  = (__hip_bfloat16*)(w + 33554432);   // 2,097,152
  __hip_bfloat16* WkvT = (__hip_bfloat16*)(w + 35651584);   // 4,194,304
  __hip_bfloat16* WpT  = (__hip_bfloat16*)(w + 39845888);   // 2,097,152
  __hip_bfloat16* Mt   = (__hip_bfloat16*)(w + 41943040);   // 8,388,608
  __hip_bfloat16* aoB  = (__hip_bfloat16*)(w + 50331648);   // 524,288
  // total 50,855,936 B
  // kv partials live in d_out (16MB of its 64MB), consumed by attn before the
  // final GEMM overwrites all of d_out. Deterministic.
  float* kvp = out;

  // 4 weight transposes only
  prep4<<<4096, 256, 0, stream>>>(Wg, Wk, Wv, Wp, WgT, WkvT, WkvT + 1024 * 1024, WpT);

  // gates: G = softmax_groups(x @ Wg), bf16 [16384,1024], fp32-A triple pipeline
  gemm_gates_f32<<<dim3(64, 4), 512, 0, stream>>>(x, WgT, G);

  // k,v split-K partials: kvp[8][256][2048] fp32 (stacked rows b*64+t), fp32-A direct
  gemm_kv<<<dim3(2, 16, 8), 256, 0, stream>>>(x, WkvT, kvp);

  // attention (+partial sum +RoPE) -> ao bf16
  attn_kernel<<<dim3(16, 4), 256, 0, stream>>>(kvp, lq, aoB);

  // Mt via MFMA
  build_mt_mfma<<<dim3(4, 16, 4), 256, 0, stream>>>(aoB, WpT, Mt);

  // out[b] = G[b] @ Mt[b]^T (fp32 out, overwrites kvp scratch)
  gemm256o<<<dim3(16, 4, 4), 512, 0, stream>>>(G, Mt, out, 1024, 1024,
                                               4096LL * 1024, 1024LL * 1024, 4096LL * 1024);
}

// Round 12
// 136.803 us; speedup vs baseline: 1.0022x; 1.0022x over previous
//
#include <hip/hip_runtime.h>
#include <hip/hip_bf16.h>

// MultiLatentAttention on MI355X.
// causal mask t<=l with L=64 => attention only over first 64 tokens.
// out[b] = softmax_groups(x@Wg) @ M[b],  M built from attn_out and Wp (MFMA).
// Round 12: revert to round-10 proven structure + (a) XCD-contiguous block remap
// on both big GEMMs, (b) attn+Mt merged (WpT staged under attention compute).

typedef __attribute__((ext_vector_type(8))) short bf16x8;
typedef __attribute__((ext_vector_type(4))) float f32x4;
typedef __attribute__((ext_vector_type(4))) unsigned short us4;

__device__ __forceinline__ void gll16(const void* g, void* l) {
  __builtin_amdgcn_global_load_lds((const __attribute__((address_space(1))) void*)g,
                                   (__attribute__((address_space(3))) void*)l, 16, 0, 0);
}

// ---------------- prep: x->bf16 (blocks 0..2047) + 4 weight transposes (2048..6143) ----------
__global__ __launch_bounds__(256)
void prep_kernel(const float* __restrict__ x, __hip_bfloat16* __restrict__ xb,
                 const float* __restrict__ Wg, const float* __restrict__ Wk,
                 const float* __restrict__ Wv, const float* __restrict__ Wp,
                 __hip_bfloat16* __restrict__ WgT, __hip_bfloat16* __restrict__ WkT,
                 __hip_bfloat16* __restrict__ WvT, __hip_bfloat16* __restrict__ WpT) {
  const int bid = blockIdx.x, tid = threadIdx.x;
  if (bid < 2048) {
    const int stride = 2048 * 256;
    for (int i = bid * 256 + tid; i < 4194304; i += stride) {
      float4 f = reinterpret_cast<const float4*>(x)[i];
      union { __hip_bfloat16 h[4]; us4 v; } u;
      u.h[0] = __float2bfloat16(f.x);
      u.h[1] = __float2bfloat16(f.y);
      u.h[2] = __float2bfloat16(f.z);
      u.h[3] = __float2bfloat16(f.w);
      reinterpret_cast<us4*>(xb)[i] = u.v;
    }
  } else {
    const int t = bid - 2048;
    const int z = t >> 10, rem = t & 1023;
    const float* W = (z == 0) ? Wg : ((z == 1) ? Wk : ((z == 2) ? Wv : Wp));
    __hip_bfloat16* Wt = (z == 0) ? WgT : ((z == 1) ? WkT : ((z == 2) ? WvT : WpT));
    __shared__ float tile[32][33];
    const int bx = (rem & 31) * 32, by = (rem >> 5) * 32;
    const int tx = tid & 31, ty = tid >> 5;  // 32x8
    #pragma unroll
    for (int j = 0; j < 32; j += 8)
      tile[ty + j][tx] = W[(size_t)(by + ty + j) * 1024 + bx + tx];
    __syncthreads();
    #pragma unroll
    for (int j = 0; j < 32; j += 8)
      Wt[(size_t)(bx + ty + j) * 1024 + by + tx] = __float2bfloat16(tile[tx][ty + j]);
  }
}

// ---------------- 256x256 2-phase pipelined bf16 GEMM (proven ~49us) + XCD remap -------------
// Launched as linear grid (256 blocks). swz=(bid&7)*32+(bid>>3) makes each XCD's 32
// blocks contiguous in (ix-fastest) tile order, so blocks sharing a B-panel land on
// the same XCD L2 -> shorter load tails at the per-iter vmcnt drain (T1 mechanism).
// LDS swizzle: 16B-chunk ^= (row&7), pre-swizzled on the GLOBAL source (gll16 dest
// linear), applied on fragment reads.
// EPI=0: fp32 store. EPI=1: per-64-column-group softmax, bf16 store (gates).
template <int EPI>
__global__ __launch_bounds__(512, 2)
void gemm256(const __hip_bfloat16* __restrict__ A, const __hip_bfloat16* __restrict__ Bt,
             void* __restrict__ Cv, int K, int ldc,
             long long astride, long long bstride, long long cstride,
             int nx, int ny) {
  __shared__ __align__(16) unsigned short SA[2][256 * 64];
  __shared__ __align__(16) unsigned short SB[2][256 * 64];
  const int tid = threadIdx.x;
  const int lane = tid & 63;
  const int w = tid >> 6;            // wave 0..7
  const int wm = w >> 2, wn = w & 3; // 2x4 wave grid; per-wave out = 128x64
  const int lr = lane & 15, lk = lane >> 4;

  const int bid = blockIdx.x;
  const int swz = (bid & 7) * 32 + (bid >> 3);   // bijective for 256 blocks
  const int ix = swz % nx;
  const int iy = (swz / nx) % ny;
  const long long b = swz / (nx * ny);
  const int m0 = ix * 256, n0 = iy * 256;

  const __hip_bfloat16* Ab = A + b * astride;
  const __hip_bfloat16* Bb = Bt + b * bstride;

  f32x4 acc[8][4] = {};

  const int NT = K >> 6;
  int buf = 0;

  auto STAGE = [&](int bsel, int kt) {
    #pragma unroll
    for (int r = 0; r < 4; ++r) {
      int c = r * 512 + tid;          // chunk 0..2047: row=c>>3, slot=c&7
      int row = c >> 3, slot = c & 7;
      int gch = slot ^ (row & 7);     // pre-swizzled global chunk
      gll16(Ab + (size_t)(m0 + row) * K + kt + gch * 8, (char*)&SA[bsel][0] + c * 16);
      gll16(Bb + (size_t)(n0 + row) * K + kt + gch * 8, (char*)&SB[bsel][0] + c * 16);
    }
  };

  STAGE(0, 0);
  __syncthreads();

  for (int t = 0; t < NT; ++t) {
    if (t + 1 < NT) STAGE(buf ^ 1, (t + 1) << 6);

    bf16x8 bfr[2][4];
    #pragma unroll
    for (int kk = 0; kk < 2; ++kk)
      #pragma unroll
      for (int ni = 0; ni < 4; ++ni) {
        int row = wn * 64 + ni * 16 + lr;
        int ch = (kk * 4 + lk) ^ (row & 7);
        bfr[kk][ni] = *(const bf16x8*)&SB[buf][row * 64 + ch * 8];
      }
    #pragma unroll
    for (int mi = 0; mi < 8; ++mi) {
      int row = wm * 128 + mi * 16 + lr;
      int ch0 = lk ^ (row & 7);
      int ch1 = (4 + lk) ^ (row & 7);
      bf16x8 a0 = *(const bf16x8*)&SA[buf][row * 64 + ch0 * 8];
      bf16x8 a1 = *(const bf16x8*)&SA[buf][row * 64 + ch1 * 8];
      #pragma unroll
      for (int ni = 0; ni < 4; ++ni)
        acc[mi][ni] = __builtin_amdgcn_mfma_f32_16x16x32_bf16(a0, bfr[0][ni], acc[mi][ni], 0, 0, 0);
      #pragma unroll
      for (int ni = 0; ni < 4; ++ni)
        acc[mi][ni] = __builtin_amdgcn_mfma_f32_16x16x32_bf16(a1, bfr[1][ni], acc[mi][ni], 0, 0, 0);
    }
    __syncthreads();
    buf ^= 1;
  }

  if (EPI == 0) {
    float* C = (float*)Cv + b * cstride;
    #pragma unroll
    for (int mi = 0; mi < 8; ++mi) {
      int r = m0 + wm * 128 + mi * 16 + lk * 4;
      #pragma unroll
      for (int ni = 0; ni < 4; ++ni) {
        int c = n0 + wn * 64 + ni * 16 + lr;
        #pragma unroll
        for (int jj = 0; jj < 4; ++jj)
          C[(size_t)(r + jj) * ldc + c] = acc[mi][ni][jj];
      }
    }
  } else {
    // Each wave's 64 columns = one softmax group (head h, l=0..63).
    __hip_bfloat16* C = (__hip_bfloat16*)Cv + b * cstride;
    #pragma unroll
    for (int mi = 0; mi < 8; ++mi) {
      #pragma unroll
      for (int jj = 0; jj < 4; ++jj) {
        float mx = -3.0e38f;
        #pragma unroll
        for (int ni = 0; ni < 4; ++ni) mx = fmaxf(mx, acc[mi][ni][jj]);
        mx = fmaxf(mx, __shfl_xor(mx, 1));
        mx = fmaxf(mx, __shfl_xor(mx, 2));
        mx = fmaxf(mx, __shfl_xor(mx, 4));
        mx = fmaxf(mx, __shfl_xor(mx, 8));
        float e[4];
        float s = 0.f;
        #pragma unroll
        for (int ni = 0; ni < 4; ++ni) { e[ni] = __expf(acc[mi][ni][jj] - mx); s += e[ni]; }
        s += __shfl_xor(s, 1);
        s += __shfl_xor(s, 2);
        s += __shfl_xor(s, 4);
        s += __shfl_xor(s, 8);
        float inv = 1.0f / s;
        int r = m0 + wm * 128 + mi * 16 + lk * 4 + jj;
        #pragma unroll
        for (int ni = 0; ni < 4; ++ni)
          C[(size_t)r * ldc + n0 + wn * 64 + ni * 16 + lr] = __float2bfloat16(e[ni] * inv);
      }
    }
  }
}

// ---------------- kv projection, split-K=8: kvp[ks][256][2048] fp32 partials ----------------
// Stacked rows (b*64+t, t<64). 128x128 tile, BK=32, 4 waves, 4 K-iters/block, grid (2,16,8).
__global__ __launch_bounds__(256)
void gemm_kv(const __hip_bfloat16* __restrict__ A, const __hip_bfloat16* __restrict__ Bt,
             float* __restrict__ kvp) {
  __shared__ __align__(16) unsigned short As[128 * 32];
  __shared__ __align__(16) unsigned short Bs[128 * 32];
  const int tid = threadIdx.x;
  const int lane = tid & 63;
  const int w = tid >> 6;
  const int wm = w >> 1, wn = w & 1;
  const int lr = lane & 15, lk = lane >> 4;
  const int m0 = blockIdx.x * 128, n0 = blockIdx.y * 128;
  const int ks = blockIdx.z;
  const int K = 1024;

  f32x4 acc[4][4] = {};
  const int r0 = tid >> 2;
  const int c8 = (tid & 3) * 8;

  auto xrow = [&](int rg) { return (size_t)(rg >> 6) * 4096 + (rg & 63); };

  for (int ki = 0; ki < 4; ++ki) {
    int kt = ks * 128 + ki * 32;
    __syncthreads();
    gll16(A + xrow(m0 + r0) * K + kt + c8,      (char*)As + (w * 64) * 16);
    gll16(Bt + (size_t)(n0 + r0) * K + kt + c8, (char*)Bs + (w * 64) * 16);
    gll16(A + xrow(m0 + 64 + r0) * K + kt + c8,      (char*)As + (256 + w * 64) * 16);
    gll16(Bt + (size_t)(n0 + 64 + r0) * K + kt + c8, (char*)Bs + (256 + w * 64) * 16);
    __syncthreads();

    bf16x8 af[4], bf[4];
    #pragma unroll
    for (int mi = 0; mi < 4; ++mi)
      af[mi] = *(const bf16x8*)&As[(wm * 64 + mi * 16 + lr) * 32 + lk * 8];
    #pragma unroll
    for (int ni = 0; ni < 4; ++ni)
      bf[ni] = *(const bf16x8*)&Bs[(wn * 64 + ni * 16 + lr) * 32 + lk * 8];
    #pragma unroll
    for (int mi = 0; mi < 4; ++mi)
      #pragma unroll
      for (int ni = 0; ni < 4; ++ni)
        acc[mi][ni] = __builtin_amdgcn_mfma_f32_16x16x32_bf16(af[mi], bf[ni], acc[mi][ni], 0, 0, 0);
  }

  float* C = kvp + (size_t)ks * 256 * 2048;
  #pragma unroll
  for (int mi = 0; mi < 4; ++mi) {
    int r = m0 + wm * 64 + mi * 16 + lk * 4;
    #pragma unroll
    for (int ni = 0; ni < 4; ++ni) {
      int c = n0 + wn * 64 + ni * 16 + lr;
      #pragma unroll
      for (int jj = 0; jj < 4; ++jj)
        C[(size_t)(r + jj) * 2048 + c] = acc[mi][ni][jj];
    }
  }
}

// ---------------- attn (split-K sum + RoPE) + MFMA Mt build, merged: grid (4ct,16h,4b) -------
// WpT slice staged via gll16 FIRST (lands under attention compute). Attention redone per
// ct-block (cheap); ao written to LDS bf16 with ^(row&7) swizzle (plain ds_write, so the
// swizzle is applied directly on the write and matched on the MFMA fragment read).
// Mt_slice[256c][64l] = WpT_slice[256c][64d] @ ao[64l][64d]^T  via 16x16x32 MFMA.
__global__ __launch_bounds__(256)
void attn_mt(const float* __restrict__ kvp, const float* __restrict__ lq,
             const __hip_bfloat16* __restrict__ WpT, __hip_bfloat16* __restrict__ Mt) {
  const int ct = blockIdx.x, h = blockIdx.y, b = blockIdx.z;
  __shared__ float Ks[64][64];
  __shared__ float Vs[64][64];
  __shared__ float S[64][65];   // S[l][t]
  __shared__ float Pt[64][65];  // Pt[t][l]
  __shared__ __align__(16) unsigned short SW[256 * 64];   // WpT slice [256c][64d], swizzled
  __shared__ __align__(16) unsigned short SAo[64 * 64];   // ao bf16 [64l][64d], swizzled
  const int tid = threadIdx.x;
  const int lane = tid & 63;
  const int w = tid >> 6;
  const int lr = lane & 15, lk = lane >> 4;

  // stage WpT slice early — overlaps the whole attention phase
  #pragma unroll
  for (int j = 0; j < 8; ++j) {
    int c2 = j * 256 + tid;
    int row = c2 >> 3, slot = c2 & 7;
    int gch = slot ^ (row & 7);
    gll16(WpT + (size_t)(ct * 256 + row) * 1024 + h * 64 + gch * 8, (char*)SW + c2 * 16);
  }

  // ---- K/V: sum 8 split-K partials + RoPE on K ----
  {
    int r = tid >> 4;            // 0..15
    int c4 = (tid & 15) * 4;     // head-dim col (pairs i0=c4/2, i0+1)
    int i0 = c4 >> 1;
    float inv0 = exp2f(-13.287712379549449f * ((float)i0 * (1.0f / 32.0f)));
    float inv1 = exp2f(-13.287712379549449f * ((float)(i0 + 1) * (1.0f / 32.0f)));
    #pragma unroll
    for (int j = 0; j < 4; ++j) {
      int row = j * 16 + r;      // t
      float4 kf = make_float4(0.f, 0.f, 0.f, 0.f);
      float4 vf = make_float4(0.f, 0.f, 0.f, 0.f);
      #pragma unroll
      for (int ks = 0; ks < 8; ++ks) {
        const float* base = kvp + ((size_t)ks * 256 + b * 64 + row) * 2048 + h * 64;
        float4 kp = *(const float4*)(base + c4);
        float4 vp = *(const float4*)(base + 1024 + c4);
        kf.x += kp.x; kf.y += kp.y; kf.z += kp.z; kf.w += kp.w;
        vf.x += vp.x; vf.y += vp.y; vf.z += vp.z; vf.w += vp.w;
      }
      float a0 = (float)row * inv0, a1 = (float)row * inv1;
      float s0 = sinf(a0), c0 = cosf(a0), s1 = sinf(a1), c1 = cosf(a1);
      *(float4*)&Ks[row][c4] = make_float4(kf.x * c0 - kf.y * s0, kf.x * s0 + kf.y * c0,
                                           kf.z * c1 - kf.w * s1, kf.z * s1 + kf.w * c1);
      *(float4*)&Vs[row][c4] = vf;
    }
  }
  __syncthreads();

  // ---- scores: thread = (l = lane, t-chunk = wave) ----
  {
    const int l = tid & 63;
    float q[64];
    const float4* lq4 = (const float4*)(lq + ((size_t)l * 16 + h) * 64);
    #pragma unroll
    for (int i = 0; i < 16; ++i) {
      float4 f = lq4[i];
      q[4 * i] = f.x; q[4 * i + 1] = f.y; q[4 * i + 2] = f.z; q[4 * i + 3] = f.w;
    }
    #pragma unroll
    for (int tl = 0; tl < 16; ++tl) {
      int t = w * 16 + tl;
      float a = 0.f;
      #pragma unroll
      for (int d4 = 0; d4 < 16; ++d4) {
        float4 kf = *(const float4*)&Ks[t][d4 * 4];
        a += q[4 * d4] * kf.x + q[4 * d4 + 1] * kf.y + q[4 * d4 + 2] * kf.z + q[4 * d4 + 3] * kf.w;
      }
      S[l][t] = a * 0.125f;
    }
  }
  __syncthreads();

  // ---- softmax: thread = (l = tid>>2, c = tid&3), causal t<=l ----
  {
    const int l = tid >> 2, c = tid & 3;
    float sv[16];
    float mx = -3.0e38f;
    #pragma unroll
    for (int i = 0; i < 16; ++i) {
      int t = c * 16 + i;
      sv[i] = S[l][t];
      if (t <= l) mx = fmaxf(mx, sv[i]);
    }
    mx = fmaxf(mx, __shfl_xor(mx, 1));
    mx = fmaxf(mx, __shfl_xor(mx, 2));
    float sum = 0.f;
    float e[16];
    #pragma unroll
    for (int i = 0; i < 16; ++i) {
      int t = c * 16 + i;
      e[i] = (t <= l) ? __expf(sv[i] - mx) : 0.f;
      sum += e[i];
    }
    sum += __shfl_xor(sum, 1);
    sum += __shfl_xor(sum, 2);
    float inv = 1.0f / sum;
    #pragma unroll
    for (int i = 0; i < 16; ++i) Pt[c * 16 + i][l] = e[i] * inv;
  }
  __syncthreads();

  // ---- PV: thread = (l = lane, d-chunk = wave); ao -> SAo bf16 swizzled ----
  {
    const int l = tid & 63;
    float o[16];
    #pragma unroll
    for (int i = 0; i < 16; ++i) o[i] = 0.f;
    for (int t = 0; t < 64; ++t) {
      float p = Pt[t][l];
      #pragma unroll
      for (int d4 = 0; d4 < 4; ++d4) {
        float4 vf = *(const float4*)&Vs[t][w * 16 + d4 * 4];
        o[4 * d4]     += p * vf.x;
        o[4 * d4 + 1] += p * vf.y;
        o[4 * d4 + 2] += p * vf.z;
        o[4 * d4 + 3] += p * vf.w;
      }
    }
    union { __hip_bfloat16 hh[8]; bf16x8 v; } p0, p1;
    #pragma unroll
    for (int i = 0; i < 8; ++i) { p0.hh[i] = __float2bfloat16(o[i]); p1.hh[i] = __float2bfloat16(o[8 + i]); }
    // logical d-chunks 2w, 2w+1 of row l at physical chunk ^ (l&7)
    *(bf16x8*)&SAo[l * 64 + ((2 * w) ^ (l & 7)) * 8]     = p0.v;
    *(bf16x8*)&SAo[l * 64 + ((2 * w + 1) ^ (l & 7)) * 8] = p1.v;
  }
  __syncthreads();  // drains SAo ds_writes AND SW gll16 (vmcnt)

  // ---- MFMA: Mt_slice = SW @ SAo^T ----
  f32x4 acc[4][4] = {};
  bf16x8 bfr[2][4];
  #pragma unroll
  for (int kk = 0; kk < 2; ++kk)
    #pragma unroll
    for (int ni = 0; ni < 4; ++ni) {
      int row = ni * 16 + lr;
      int ch = (kk * 4 + lk) ^ (row & 7);
      bfr[kk][ni] = *(const bf16x8*)&SAo[row * 64 + ch * 8];
    }
  #pragma unroll
  for (int mi = 0; mi < 4; ++mi) {
    int row = w * 64 + mi * 16 + lr;
    int ch0 = lk ^ (row & 7);
    int ch1 = (4 + lk) ^ (row & 7);
    bf16x8 a0 = *(const bf16x8*)&SW[row * 64 + ch0 * 8];
    bf16x8 a1 = *(const bf16x8*)&SW[row * 64 + ch1 * 8];
    #pragma unroll
    for (int ni = 0; ni < 4; ++ni)
      acc[mi][ni] = __builtin_amdgcn_mfma_f32_16x16x32_bf16(a0, bfr[0][ni], acc[mi][ni], 0, 0, 0);
    #pragma unroll
    for (int ni = 0; ni < 4; ++ni)
      acc[mi][ni] = __builtin_amdgcn_mfma_f32_16x16x32_bf16(a1, bfr[1][ni], acc[mi][ni], 0, 0, 0);
  }

  // C-layout: row(c) = ct*256 + w*64 + mi*16 + lk*4 + jj, col(l) = ni*16 + lr
  #pragma unroll
  for (int mi = 0; mi < 4; ++mi) {
    int c = ct * 256 + w * 64 + mi * 16 + lk * 4;
    #pragma unroll
    for (int ni = 0; ni < 4; ++ni) {
      int l = ni * 16 + lr;
      #pragma unroll
      for (int jj = 0; jj < 4; ++jj)
        Mt[((size_t)b * 1024 + c + jj) * 1024 + h * 64 + l] = __float2bfloat16(acc[mi][ni][jj]);
    }
  }
}

extern "C" void kernel_launch(void* const* d_in, const int* in_sizes, int n_in,
                              void* d_out, int out_size, void* d_ws, size_t ws_size,
                              hipStream_t stream) {
  const float* x  = (const float*)d_in[0];
  const float* lq = (const float*)d_in[1];
  const float* Wk = (const float*)d_in[2];
  const float* Wv = (const float*)d_in[3];
  const float* Wg = (const float*)d_in[4];
  const float* Wp = (const float*)d_in[5];
  float* out = (float*)d_out;

  // workspace layout (bytes)
  char* w = (char*)d_ws;
  __hip_bfloat16* xb   = (__hip_bfloat16*)(w);              // 33,554,432
  __hip_bfloat16* G    = (__hip_bfloat16*)(w + 33554432);   // 33,554,432
  __hip_bfloat16* WgT  = (__hip_bfloat16*)(w + 67108864);   // 2,097,152
  __hip_bfloat16* WkvT = (__hip_bfloat16*)(w + 69206016);   // 4,194,304
  __hip_bfloat16* WpT  = (__hip_bfloat16*)(w + 73400320);   // 2,097,152
  __hip_bfloat16* Mt   = (__hip_bfloat16*)(w + 75497472);   // 8,388,608
  // total 83,886,080 B
  // kv partials live in d_out (16MB of its 64MB), consumed by attn_mt before
  // the final GEMM overwrites all of d_out. Deterministic.
  float* kvp = out;

  // x->bf16 + 4 weight transposes, one launch
  prep_kernel<<<6144, 256, 0, stream>>>(x, xb, Wg, Wk, Wv, Wp,
                                        WgT, WkvT, WkvT + 1024 * 1024, WpT);

  // gates: G = softmax_groups(x @ Wg), bf16 [16384,1024]; XCD-remapped grid
  gemm256<1><<<256, 512, 0, stream>>>(xb, WgT, G, 1024, 1024, 0LL, 0LL, 0LL, 64, 4);

  // k,v split-K partials: kvp[8][256][2048] fp32 (stacked rows b*64+t)
  gemm_kv<<<dim3(2, 16, 8), 256, 0, stream>>>(xb, WkvT, kvp);

  // attention (+partial sum +RoPE) + MFMA Mt build, merged
  attn_mt<<<dim3(4, 16, 4), 256, 0, stream>>>(kvp, lq, WpT, Mt);

  // out[b] = G[b] @ Mt[b]^T (fp32 out, overwrites kvp scratch); XCD-remapped grid
  gemm256<0><<<256, 512, 0, stream>>>(G, Mt, out, 1024, 1024,
                                      4096LL * 1024, 1024LL * 1024, 4096LL * 1024, 16, 4);
}

// Round 13
// 135.104 us; speedup vs baseline: 1.0148x; 1.0126x over previous
//
#include <hip/hip_runtime.h>
#include <hip/hip_bf16.h>

// MultiLatentAttention on MI355X.
// causal mask t<=l with L=64 => attention only over first 64 tokens.
// out[b] = softmax_groups(x@Wg) @ M[b],  M built from attn_out and Wp (MFMA).
// Round 13: revert XCD remap (it broke A-panel XCD-locality, FETCH x2.7);
// gates GEMM -> 128^2/BK=32/dbuf/32KiB (4 blocks/CU co-resident, m97 mechanism);
// out GEMM stays proven 256^2 2-phase (control). attn_mt merge kept.

typedef __attribute__((ext_vector_type(8))) short bf16x8;
typedef __attribute__((ext_vector_type(4))) float f32x4;
typedef __attribute__((ext_vector_type(4))) unsigned short us4;

__device__ __forceinline__ void gll16(const void* g, void* l) {
  __builtin_amdgcn_global_load_lds((const __attribute__((address_space(1))) void*)g,
                                   (__attribute__((address_space(3))) void*)l, 16, 0, 0);
}

// ---------------- prep: x->bf16 (blocks 0..2047) + 4 weight transposes (2048..6143) ----------
__global__ __launch_bounds__(256)
void prep_kernel(const float* __restrict__ x, __hip_bfloat16* __restrict__ xb,
                 const float* __restrict__ Wg, const float* __restrict__ Wk,
                 const float* __restrict__ Wv, const float* __restrict__ Wp,
                 __hip_bfloat16* __restrict__ WgT, __hip_bfloat16* __restrict__ WkT,
                 __hip_bfloat16* __restrict__ WvT, __hip_bfloat16* __restrict__ WpT) {
  const int bid = blockIdx.x, tid = threadIdx.x;
  if (bid < 2048) {
    const int stride = 2048 * 256;
    for (int i = bid * 256 + tid; i < 4194304; i += stride) {
      float4 f = reinterpret_cast<const float4*>(x)[i];
      union { __hip_bfloat16 h[4]; us4 v; } u;
      u.h[0] = __float2bfloat16(f.x);
      u.h[1] = __float2bfloat16(f.y);
      u.h[2] = __float2bfloat16(f.z);
      u.h[3] = __float2bfloat16(f.w);
      reinterpret_cast<us4*>(xb)[i] = u.v;
    }
  } else {
    const int t = bid - 2048;
    const int z = t >> 10, rem = t & 1023;
    const float* W = (z == 0) ? Wg : ((z == 1) ? Wk : ((z == 2) ? Wv : Wp));
    __hip_bfloat16* Wt = (z == 0) ? WgT : ((z == 1) ? WkT : ((z == 2) ? WvT : WpT));
    __shared__ float tile[32][33];
    const int bx = (rem & 31) * 32, by = (rem >> 5) * 32;
    const int tx = tid & 31, ty = tid >> 5;  // 32x8
    #pragma unroll
    for (int j = 0; j < 32; j += 8)
      tile[ty + j][tx] = W[(size_t)(by + ty + j) * 1024 + bx + tx];
    __syncthreads();
    #pragma unroll
    for (int j = 0; j < 32; j += 8)
      Wt[(size_t)(bx + ty + j) * 1024 + by + tx] = __float2bfloat16(tile[tx][ty + j]);
  }
}

// ---------------- gates GEMM: 128x128 tile, BK=32, double-buffered, 4 blocks/CU --------------
// 4 waves (2x2, per-wave 64x64), 32KiB LDS, __launch_bounds__(256,4) caps VGPR at 128 so
// 4 independent blocks co-reside per CU — cross-block overlap hides each block's
// vmcnt-drain+barrier (m97 mechanism; 2-phase prefetch within block as well).
// Rows are 64B = 4 chunks; swizzle ch = lk ^ ((row>>1)&3): 16 frag-lanes -> 8 bank-starts
// x 2-way (free). Pre-swizzled on the GLOBAL source (gll16 dest linear), matched on reads.
// Epilogue: per-64-column-group softmax, bf16 store (gates).
__global__ __launch_bounds__(256, 4)
void gemm128d(const __hip_bfloat16* __restrict__ A, const __hip_bfloat16* __restrict__ Bt,
              __hip_bfloat16* __restrict__ G) {
  __shared__ __align__(16) unsigned short SA[2][128 * 32];
  __shared__ __align__(16) unsigned short SB[2][128 * 32];
  const int tid = threadIdx.x;
  const int lane = tid & 63;
  const int w = tid >> 6;            // wave 0..3
  const int wm = w >> 1, wn = w & 1; // 2x2 wave grid, per-wave 64x64
  const int lr = lane & 15, lk = lane >> 4;
  const int m0 = blockIdx.x * 128, n0 = blockIdx.y * 128;
  const int K = 1024;

  f32x4 acc[4][4] = {};

  auto STAGE = [&](int bsel, int kt) {
    #pragma unroll
    for (int r = 0; r < 2; ++r) {
      int c = r * 256 + tid;          // chunk 0..511: row=c>>2, slot=c&3
      int row = c >> 2, slot = c & 3;
      int gs = slot ^ ((row >> 1) & 3);   // pre-swizzled global slot
      gll16(A + (size_t)(m0 + row) * K + kt + gs * 8, (char*)&SA[bsel][0] + c * 16);
      gll16(Bt + (size_t)(n0 + row) * K + kt + gs * 8, (char*)&SB[bsel][0] + c * 16);
    }
  };

  STAGE(0, 0);
  __syncthreads();

  int buf = 0;
  for (int t = 0; t < 32; ++t) {
    if (t + 1 < 32) STAGE(buf ^ 1, (t + 1) << 5);

    bf16x8 bfr[4];
    #pragma unroll
    for (int ni = 0; ni < 4; ++ni) {
      int row = wn * 64 + ni * 16 + lr;
      int ch = lk ^ ((row >> 1) & 3);
      bfr[ni] = *(const bf16x8*)&SB[buf][row * 32 + ch * 8];
    }
    #pragma unroll
    for (int mi = 0; mi < 4; ++mi) {
      int row = wm * 64 + mi * 16 + lr;
      int ch = lk ^ ((row >> 1) & 3);
      bf16x8 a = *(const bf16x8*)&SA[buf][row * 32 + ch * 8];
      #pragma unroll
      for (int ni = 0; ni < 4; ++ni)
        acc[mi][ni] = __builtin_amdgcn_mfma_f32_16x16x32_bf16(a, bfr[ni], acc[mi][ni], 0, 0, 0);
    }
    __syncthreads();
    buf ^= 1;
  }

  // Each wave's 64 columns = one softmax group (head h, l=0..63).
  #pragma unroll
  for (int mi = 0; mi < 4; ++mi) {
    #pragma unroll
    for (int jj = 0; jj < 4; ++jj) {
      float mx = -3.0e38f;
      #pragma unroll
      for (int ni = 0; ni < 4; ++ni) mx = fmaxf(mx, acc[mi][ni][jj]);
      mx = fmaxf(mx, __shfl_xor(mx, 1));
      mx = fmaxf(mx, __shfl_xor(mx, 2));
      mx = fmaxf(mx, __shfl_xor(mx, 4));
      mx = fmaxf(mx, __shfl_xor(mx, 8));
      float e[4];
      float s = 0.f;
      #pragma unroll
      for (int ni = 0; ni < 4; ++ni) { e[ni] = __expf(acc[mi][ni][jj] - mx); s += e[ni]; }
      s += __shfl_xor(s, 1);
      s += __shfl_xor(s, 2);
      s += __shfl_xor(s, 4);
      s += __shfl_xor(s, 8);
      float inv = 1.0f / s;
      int r = m0 + wm * 64 + mi * 16 + lk * 4 + jj;
      #pragma unroll
      for (int ni = 0; ni < 4; ++ni)
        G[(size_t)r * 1024 + n0 + wn * 64 + ni * 16 + lr] = __float2bfloat16(e[ni] * inv);
    }
  }
}

// ---------------- 256x256 2-phase pipelined bf16 GEMM (proven ~49us) — out projection --------
__global__ __launch_bounds__(512, 2)
void gemm256o(const __hip_bfloat16* __restrict__ A, const __hip_bfloat16* __restrict__ Bt,
              float* __restrict__ Cv, int K, int ldc,
              long long astride, long long bstride, long long cstride) {
  __shared__ __align__(16) unsigned short SA[2][256 * 64];
  __shared__ __align__(16) unsigned short SB[2][256 * 64];
  const int tid = threadIdx.x;
  const int lane = tid & 63;
  const int w = tid >> 6;
  const int wm = w >> 2, wn = w & 3;
  const int lr = lane & 15, lk = lane >> 4;
  const int m0 = blockIdx.x * 256, n0 = blockIdx.y * 256;
  const long long b = blockIdx.z;
  const __hip_bfloat16* Ab = A + b * astride;
  const __hip_bfloat16* Bb = Bt + b * bstride;

  f32x4 acc[8][4] = {};

  const int NT = K >> 6;
  int buf = 0;

  auto STAGE = [&](int bsel, int kt) {
    #pragma unroll
    for (int r = 0; r < 4; ++r) {
      int c = r * 512 + tid;
      int row = c >> 3, slot = c & 7;
      int gch = slot ^ (row & 7);
      gll16(Ab + (size_t)(m0 + row) * K + kt + gch * 8, (char*)&SA[bsel][0] + c * 16);
      gll16(Bb + (size_t)(n0 + row) * K + kt + gch * 8, (char*)&SB[bsel][0] + c * 16);
    }
  };

  STAGE(0, 0);
  __syncthreads();

  for (int t = 0; t < NT; ++t) {
    if (t + 1 < NT) STAGE(buf ^ 1, (t + 1) << 6);

    bf16x8 bfr[2][4];
    #pragma unroll
    for (int kk = 0; kk < 2; ++kk)
      #pragma unroll
      for (int ni = 0; ni < 4; ++ni) {
        int row = wn * 64 + ni * 16 + lr;
        int ch = (kk * 4 + lk) ^ (row & 7);
        bfr[kk][ni] = *(const bf16x8*)&SB[buf][row * 64 + ch * 8];
      }
    #pragma unroll
    for (int mi = 0; mi < 8; ++mi) {
      int row = wm * 128 + mi * 16 + lr;
      int ch0 = lk ^ (row & 7);
      int ch1 = (4 + lk) ^ (row & 7);
      bf16x8 a0 = *(const bf16x8*)&SA[buf][row * 64 + ch0 * 8];
      bf16x8 a1 = *(const bf16x8*)&SA[buf][row * 64 + ch1 * 8];
      #pragma unroll
      for (int ni = 0; ni < 4; ++ni)
        acc[mi][ni] = __builtin_amdgcn_mfma_f32_16x16x32_bf16(a0, bfr[0][ni], acc[mi][ni], 0, 0, 0);
      #pragma unroll
      for (int ni = 0; ni < 4; ++ni)
        acc[mi][ni] = __builtin_amdgcn_mfma_f32_16x16x32_bf16(a1, bfr[1][ni], acc[mi][ni], 0, 0, 0);
    }
    __syncthreads();
    buf ^= 1;
  }

  float* C = Cv + b * cstride;
  #pragma unroll
  for (int mi = 0; mi < 8; ++mi) {
    int r = m0 + wm * 128 + mi * 16 + lk * 4;
    #pragma unroll
    for (int ni = 0; ni < 4; ++ni) {
      int c = n0 + wn * 64 + ni * 16 + lr;
      #pragma unroll
      for (int jj = 0; jj < 4; ++jj)
        C[(size_t)(r + jj) * ldc + c] = acc[mi][ni][jj];
    }
  }
}

// ---------------- kv projection, split-K=8: kvp[ks][256][2048] fp32 partials ----------------
__global__ __launch_bounds__(256)
void gemm_kv(const __hip_bfloat16* __restrict__ A, const __hip_bfloat16* __restrict__ Bt,
             float* __restrict__ kvp) {
  __shared__ __align__(16) unsigned short As[128 * 32];
  __shared__ __align__(16) unsigned short Bs[128 * 32];
  const int tid = threadIdx.x;
  const int lane = tid & 63;
  const int w = tid >> 6;
  const int wm = w >> 1, wn = w & 1;
  const int lr = lane & 15, lk = lane >> 4;
  const int m0 = blockIdx.x * 128, n0 = blockIdx.y * 128;
  const int ks = blockIdx.z;
  const int K = 1024;

  f32x4 acc[4][4] = {};
  const int r0 = tid >> 2;
  const int c8 = (tid & 3) * 8;

  auto xrow = [&](int rg) { return (size_t)(rg >> 6) * 4096 + (rg & 63); };

  for (int ki = 0; ki < 4; ++ki) {
    int kt = ks * 128 + ki * 32;
    __syncthreads();
    gll16(A + xrow(m0 + r0) * K + kt + c8,      (char*)As + (w * 64) * 16);
    gll16(Bt + (size_t)(n0 + r0) * K + kt + c8, (char*)Bs + (w * 64) * 16);
    gll16(A + xrow(m0 + 64 + r0) * K + kt + c8,      (char*)As + (256 + w * 64) * 16);
    gll16(Bt + (size_t)(n0 + 64 + r0) * K + kt + c8, (char*)Bs + (256 + w * 64) * 16);
    __syncthreads();

    bf16x8 af[4], bf[4];
    #pragma unroll
    for (int mi = 0; mi < 4; ++mi)
      af[mi] = *(const bf16x8*)&As[(wm * 64 + mi * 16 + lr) * 32 + lk * 8];
    #pragma unroll
    for (int ni = 0; ni < 4; ++ni)
      bf[ni] = *(const bf16x8*)&Bs[(wn * 64 + ni * 16 + lr) * 32 + lk * 8];
    #pragma unroll
    for (int mi = 0; mi < 4; ++mi)
      #pragma unroll
      for (int ni = 0; ni < 4; ++ni)
        acc[mi][ni] = __builtin_amdgcn_mfma_f32_16x16x32_bf16(af[mi], bf[ni], acc[mi][ni], 0, 0, 0);
  }

  float* C = kvp + (size_t)ks * 256 * 2048;
  #pragma unroll
  for (int mi = 0; mi < 4; ++mi) {
    int r = m0 + wm * 64 + mi * 16 + lk * 4;
    #pragma unroll
    for (int ni = 0; ni < 4; ++ni) {
      int c = n0 + wn * 64 + ni * 16 + lr;
      #pragma unroll
      for (int jj = 0; jj < 4; ++jj)
        C[(size_t)(r + jj) * 2048 + c] = acc[mi][ni][jj];
    }
  }
}

// ---------------- attn (split-K sum + RoPE) + MFMA Mt build, merged: grid (4ct,16h,4b) -------
__global__ __launch_bounds__(256)
void attn_mt(const float* __restrict__ kvp, const float* __restrict__ lq,
             const __hip_bfloat16* __restrict__ WpT, __hip_bfloat16* __restrict__ Mt) {
  const int ct = blockIdx.x, h = blockIdx.y, b = blockIdx.z;
  __shared__ float Ks[64][64];
  __shared__ float Vs[64][64];
  __shared__ float S[64][65];   // S[l][t]
  __shared__ float Pt[64][65];  // Pt[t][l]
  __shared__ __align__(16) unsigned short SW[256 * 64];   // WpT slice [256c][64d], swizzled
  __shared__ __align__(16) unsigned short SAo[64 * 64];   // ao bf16 [64l][64d], swizzled
  const int tid = threadIdx.x;
  const int lane = tid & 63;
  const int w = tid >> 6;
  const int lr = lane & 15, lk = lane >> 4;

  // stage WpT slice early — overlaps the whole attention phase
  #pragma unroll
  for (int j = 0; j < 8; ++j) {
    int c2 = j * 256 + tid;
    int row = c2 >> 3, slot = c2 & 7;
    int gch = slot ^ (row & 7);
    gll16(WpT + (size_t)(ct * 256 + row) * 1024 + h * 64 + gch * 8, (char*)SW + c2 * 16);
  }

  // ---- K/V: sum 8 split-K partials + RoPE on K ----
  {
    int r = tid >> 4;            // 0..15
    int c4 = (tid & 15) * 4;     // head-dim col (pairs i0=c4/2, i0+1)
    int i0 = c4 >> 1;
    float inv0 = exp2f(-13.287712379549449f * ((float)i0 * (1.0f / 32.0f)));
    float inv1 = exp2f(-13.287712379549449f * ((float)(i0 + 1) * (1.0f / 32.0f)));
    #pragma unroll
    for (int j = 0; j < 4; ++j) {
      int row = j * 16 + r;      // t
      float4 kf = make_float4(0.f, 0.f, 0.f, 0.f);
      float4 vf = make_float4(0.f, 0.f, 0.f, 0.f);
      #pragma unroll
      for (int ks = 0; ks < 8; ++ks) {
        const float* base = kvp + ((size_t)ks * 256 + b * 64 + row) * 2048 + h * 64;
        float4 kp = *(const float4*)(base + c4);
        float4 vp = *(const float4*)(base + 1024 + c4);
        kf.x += kp.x; kf.y += kp.y; kf.z += kp.z; kf.w += kp.w;
        vf.x += vp.x; vf.y += vp.y; vf.z += vp.z; vf.w += vp.w;
      }
      float a0 = (float)row * inv0, a1 = (float)row * inv1;
      float s0 = sinf(a0), c0 = cosf(a0), s1 = sinf(a1), c1 = cosf(a1);
      *(float4*)&Ks[row][c4] = make_float4(kf.x * c0 - kf.y * s0, kf.x * s0 + kf.y * c0,
                                           kf.z * c1 - kf.w * s1, kf.z * s1 + kf.w * c1);
      *(float4*)&Vs[row][c4] = vf;
    }
  }
  __syncthreads();

  // ---- scores: thread = (l = lane, t-chunk = wave) ----
  {
    const int l = tid & 63;
    float q[64];
    const float4* lq4 = (const float4*)(lq + ((size_t)l * 16 + h) * 64);
    #pragma unroll
    for (int i = 0; i < 16; ++i) {
      float4 f = lq4[i];
      q[4 * i] = f.x; q[4 * i + 1] = f.y; q[4 * i + 2] = f.z; q[4 * i + 3] = f.w;
    }
    #pragma unroll
    for (int tl = 0; tl < 16; ++tl) {
      int t = w * 16 + tl;
      float a = 0.f;
      #pragma unroll
      for (int d4 = 0; d4 < 16; ++d4) {
        float4 kf = *(const float4*)&Ks[t][d4 * 4];
        a += q[4 * d4] * kf.x + q[4 * d4 + 1] * kf.y + q[4 * d4 + 2] * kf.z + q[4 * d4 + 3] * kf.w;
      }
      S[l][t] = a * 0.125f;
    }
  }
  __syncthreads();

  // ---- softmax: thread = (l = tid>>2, c = tid&3), causal t<=l ----
  {
    const int l = tid >> 2, c = tid & 3;
    float sv[16];
    float mx = -3.0e38f;
    #pragma unroll
    for (int i = 0; i < 16; ++i) {
      int t = c * 16 + i;
      sv[i] = S[l][t];
      if (t <= l) mx = fmaxf(mx, sv[i]);
    }
    mx = fmaxf(mx, __shfl_xor(mx, 1));
    mx = fmaxf(mx, __shfl_xor(mx, 2));
    float sum = 0.f;
    float e[16];
    #pragma unroll
    for (int i = 0; i < 16; ++i) {
      int t = c * 16 + i;
      e[i] = (t <= l) ? __expf(sv[i] - mx) : 0.f;
      sum += e[i];
    }
    sum += __shfl_xor(sum, 1);
    sum += __shfl_xor(sum, 2);
    float inv = 1.0f / sum;
    #pragma unroll
    for (int i = 0; i < 16; ++i) Pt[c * 16 + i][l] = e[i] * inv;
  }
  __syncthreads();

  // ---- PV: thread = (l = lane, d-chunk = wave); ao -> SAo bf16 swizzled ----
  {
    const int l = tid & 63;
    float o[16];
    #pragma unroll
    for (int i = 0; i < 16; ++i) o[i] = 0.f;
    for (int t = 0; t < 64; ++t) {
      float p = Pt[t][l];
      #pragma unroll
      for (int d4 = 0; d4 < 4; ++d4) {
        float4 vf = *(const float4*)&Vs[t][w * 16 + d4 * 4];
        o[4 * d4]     += p * vf.x;
        o[4 * d4 + 1] += p * vf.y;
        o[4 * d4 + 2] += p * vf.z;
        o[4 * d4 + 3] += p * vf.w;
      }
    }
    union { __hip_bfloat16 hh[8]; bf16x8 v; } p0, p1;
    #pragma unroll
    for (int i = 0; i < 8; ++i) { p0.hh[i] = __float2bfloat16(o[i]); p1.hh[i] = __float2bfloat16(o[8 + i]); }
    // logical d-chunks 2w, 2w+1 of row l at physical chunk ^ (l&7)
    *(bf16x8*)&SAo[l * 64 + ((2 * w) ^ (l & 7)) * 8]     = p0.v;
    *(bf16x8*)&SAo[l * 64 + ((2 * w + 1) ^ (l & 7)) * 8] = p1.v;
  }
  __syncthreads();  // drains SAo ds_writes AND SW gll16 (vmcnt)

  // ---- MFMA: Mt_slice = SW @ SAo^T ----
  f32x4 acc[4][4] = {};
  bf16x8 bfr[2][4];
  #pragma unroll
  for (int kk = 0; kk < 2; ++kk)
    #pragma unroll
    for (int ni = 0; ni < 4; ++ni) {
      int row = ni * 16 + lr;
      int ch = (kk * 4 + lk) ^ (row & 7);
      bfr[kk][ni] = *(const bf16x8*)&SAo[row * 64 + ch * 8];
    }
  #pragma unroll
  for (int mi = 0; mi < 4; ++mi) {
    int row = w * 64 + mi * 16 + lr;
    int ch0 = lk ^ (row & 7);
    int ch1 = (4 + lk) ^ (row & 7);
    bf16x8 a0 = *(const bf16x8*)&SW[row * 64 + ch0 * 8];
    bf16x8 a1 = *(const bf16x8*)&SW[row * 64 + ch1 * 8];
    #pragma unroll
    for (int ni = 0; ni < 4; ++ni)
      acc[mi][ni] = __builtin_amdgcn_mfma_f32_16x16x32_bf16(a0, bfr[0][ni], acc[mi][ni], 0, 0, 0);
    #pragma unroll
    for (int ni = 0; ni < 4; ++ni)
      acc[mi][ni] = __builtin_amdgcn_mfma_f32_16x16x32_bf16(a1, bfr[1][ni], acc[mi][ni], 0, 0, 0);
  }

  // C-layout: row(c) = ct*256 + w*64 + mi*16 + lk*4 + jj, col(l) = ni*16 + lr
  #pragma unroll
  for (int mi = 0; mi < 4; ++mi) {
    int c = ct * 256 + w * 64 + mi * 16 + lk * 4;
    #pragma unroll
    for (int ni = 0; ni < 4; ++ni) {
      int l = ni * 16 + lr;
      #pragma unroll
      for (int jj = 0; jj < 4; ++jj)
        Mt[((size_t)b * 1024 + c + jj) * 1024 + h * 64 + l] = __float2bfloat16(acc[mi][ni][jj]);
    }
  }
}

extern "C" void kernel_launch(void* const* d_in, const int* in_sizes, int n_in,
                              void* d_out, int out_size, void* d_ws, size_t ws_size,
                              hipStream_t stream) {
  const float* x  = (const float*)d_in[0];
  const float* lq = (const float*)d_in[1];
  const float* Wk = (const float*)d_in[2];
  const float* Wv = (const float*)d_in[3];
  const float* Wg = (const float*)d_in[4];
  const float* Wp = (const float*)d_in[5];
  float* out = (float*)d_out;

  // workspace layout (bytes)
  char* w = (char*)d_ws;
  __hip_bfloat16* xb   = (__hip_bfloat16*)(w);              // 33,554,432
  __hip_bfloat16* G    = (__hip_bfloat16*)(w + 33554432);   // 33,554,432
  __hip_bfloat16* WgT  = (__hip_bfloat16*)(w + 67108864);   // 2,097,152
  __hip_bfloat16* WkvT = (__hip_bfloat16*)(w + 69206016);   // 4,194,304
  __hip_bfloat16* WpT  = (__hip_bfloat16*)(w + 73400320);   // 2,097,152
  __hip_bfloat16* Mt   = (__hip_bfloat16*)(w + 75497472);   // 8,388,608
  // total 83,886,080 B
  // kv partials live in d_out (16MB of its 64MB), consumed by attn_mt before
  // the final GEMM overwrites all of d_out. Deterministic.
  float* kvp = out;

  // x->bf16 + 4 weight transposes, one launch
  prep_kernel<<<6144, 256, 0, stream>>>(x, xb, Wg, Wk, Wv, Wp,
                                        WgT, WkvT, WkvT + 1024 * 1024, WpT);

  // gates: G = softmax_groups(x @ Wg), bf16 [16384,1024] — 128^2/BK32/dbuf, 4 blocks/CU
  gemm128d<<<dim3(128, 8), 256, 0, stream>>>(xb, WgT, G);

  // k,v split-K partials: kvp[8][256][2048] fp32 (stacked rows b*64+t)
  gemm_kv<<<dim3(2, 16, 8), 256, 0, stream>>>(xb, WkvT, kvp);

  // attention (+partial sum +RoPE) + MFMA Mt build, merged
  attn_mt<<<dim3(4, 16, 4), 256, 0, stream>>>(kvp, lq, WpT, Mt);

  // out[b] = G[b] @ Mt[b]^T (fp32 out, overwrites kvp scratch) — proven control
  gemm256o<<<dim3(16, 4, 4), 512, 0, stream>>>(G, Mt, out, 1024, 1024,
                                               4096LL * 1024, 1024LL * 1024, 4096LL * 1024);
}

// Round 14
// 133.739 us; speedup vs baseline: 1.0252x; 1.0102x over previous
//
#include <hip/hip_runtime.h>
#include <hip/hip_bf16.h>

// MultiLatentAttention on MI355X.
// causal mask t<=l with L=64 => attention only over first 64 tokens.
// out[b] = softmax_groups(x@Wg) @ M[b],  M built from attn_out and Wp (MFMA).
// Round 14: consolidation — both big GEMMs on the proven 256^2 2-phase kernel
// (48.8us each; 6 schedule variants bracketed it), merged attn+Mt, split-K kv,
// single prep launch, no XCD remap (default dispatch is XCD-optimal here).

typedef __attribute__((ext_vector_type(8))) short bf16x8;
typedef __attribute__((ext_vector_type(4))) float f32x4;
typedef __attribute__((ext_vector_type(4))) unsigned short us4;

__device__ __forceinline__ void gll16(const void* g, void* l) {
  __builtin_amdgcn_global_load_lds((const __attribute__((address_space(1))) void*)g,
                                   (__attribute__((address_space(3))) void*)l, 16, 0, 0);
}

// ---------------- prep: x->bf16 (blocks 0..2047) + 4 weight transposes (2048..6143) ----------
__global__ __launch_bounds__(256)
void prep_kernel(const float* __restrict__ x, __hip_bfloat16* __restrict__ xb,
                 const float* __restrict__ Wg, const float* __restrict__ Wk,
                 const float* __restrict__ Wv, const float* __restrict__ Wp,
                 __hip_bfloat16* __restrict__ WgT, __hip_bfloat16* __restrict__ WkT,
                 __hip_bfloat16* __restrict__ WvT, __hip_bfloat16* __restrict__ WpT) {
  const int bid = blockIdx.x, tid = threadIdx.x;
  if (bid < 2048) {
    const int stride = 2048 * 256;
    for (int i = bid * 256 + tid; i < 4194304; i += stride) {
      float4 f = reinterpret_cast<const float4*>(x)[i];
      union { __hip_bfloat16 h[4]; us4 v; } u;
      u.h[0] = __float2bfloat16(f.x);
      u.h[1] = __float2bfloat16(f.y);
      u.h[2] = __float2bfloat16(f.z);
      u.h[3] = __float2bfloat16(f.w);
      reinterpret_cast<us4*>(xb)[i] = u.v;
    }
  } else {
    const int t = bid - 2048;
    const int z = t >> 10, rem = t & 1023;
    const float* W = (z == 0) ? Wg : ((z == 1) ? Wk : ((z == 2) ? Wv : Wp));
    __hip_bfloat16* Wt = (z == 0) ? WgT : ((z == 1) ? WkT : ((z == 2) ? WvT : WpT));
    __shared__ float tile[32][33];
    const int bx = (rem & 31) * 32, by = (rem >> 5) * 32;
    const int tx = tid & 31, ty = tid >> 5;  // 32x8
    #pragma unroll
    for (int j = 0; j < 32; j += 8)
      tile[ty + j][tx] = W[(size_t)(by + ty + j) * 1024 + bx + tx];
    __syncthreads();
    #pragma unroll
    for (int j = 0; j < 32; j += 8)
      Wt[(size_t)(bx + ty + j) * 1024 + by + tx] = __float2bfloat16(tile[tx][ty + j]);
  }
}

// ---------------- 256x256 2-phase pipelined bf16 GEMM (proven ~48.8us) ----------------
// 8 waves (2Mx4N), BK=64, double-buffered 128KiB LDS. LDS swizzle: 16B-chunk ^= (row&7),
// pre-swizzled on the GLOBAL source (gll16 dest linear), applied on fragment reads.
// EPI=0: fp32 store. EPI=1: per-64-column-group softmax, bf16 store (gates).
template <int EPI>
__global__ __launch_bounds__(512, 2)
void gemm256(const __hip_bfloat16* __restrict__ A, const __hip_bfloat16* __restrict__ Bt,
             void* __restrict__ Cv, int K, int ldc,
             long long astride, long long bstride, long long cstride) {
  __shared__ __align__(16) unsigned short SA[2][256 * 64];
  __shared__ __align__(16) unsigned short SB[2][256 * 64];
  const int tid = threadIdx.x;
  const int lane = tid & 63;
  const int w = tid >> 6;            // wave 0..7
  const int wm = w >> 2, wn = w & 3; // 2x4 wave grid; per-wave out = 128x64
  const int lr = lane & 15, lk = lane >> 4;
  const int m0 = blockIdx.x * 256, n0 = blockIdx.y * 256;
  const long long b = blockIdx.z;
  const __hip_bfloat16* Ab = A + b * astride;
  const __hip_bfloat16* Bb = Bt + b * bstride;

  f32x4 acc[8][4] = {};

  const int NT = K >> 6;
  int buf = 0;

  auto STAGE = [&](int bsel, int kt) {
    #pragma unroll
    for (int r = 0; r < 4; ++r) {
      int c = r * 512 + tid;          // chunk 0..2047: row=c>>3, slot=c&7
      int row = c >> 3, slot = c & 7;
      int gch = slot ^ (row & 7);     // pre-swizzled global chunk
      gll16(Ab + (size_t)(m0 + row) * K + kt + gch * 8, (char*)&SA[bsel][0] + c * 16);
      gll16(Bb + (size_t)(n0 + row) * K + kt + gch * 8, (char*)&SB[bsel][0] + c * 16);
    }
  };

  STAGE(0, 0);
  __syncthreads();

  for (int t = 0; t < NT; ++t) {
    if (t + 1 < NT) STAGE(buf ^ 1, (t + 1) << 6);

    bf16x8 bfr[2][4];
    #pragma unroll
    for (int kk = 0; kk < 2; ++kk)
      #pragma unroll
      for (int ni = 0; ni < 4; ++ni) {
        int row = wn * 64 + ni * 16 + lr;
        int ch = (kk * 4 + lk) ^ (row & 7);
        bfr[kk][ni] = *(const bf16x8*)&SB[buf][row * 64 + ch * 8];
      }
    #pragma unroll
    for (int mi = 0; mi < 8; ++mi) {
      int row = wm * 128 + mi * 16 + lr;
      int ch0 = lk ^ (row & 7);
      int ch1 = (4 + lk) ^ (row & 7);
      bf16x8 a0 = *(const bf16x8*)&SA[buf][row * 64 + ch0 * 8];
      bf16x8 a1 = *(const bf16x8*)&SA[buf][row * 64 + ch1 * 8];
      #pragma unroll
      for (int ni = 0; ni < 4; ++ni)
        acc[mi][ni] = __builtin_amdgcn_mfma_f32_16x16x32_bf16(a0, bfr[0][ni], acc[mi][ni], 0, 0, 0);
      #pragma unroll
      for (int ni = 0; ni < 4; ++ni)
        acc[mi][ni] = __builtin_amdgcn_mfma_f32_16x16x32_bf16(a1, bfr[1][ni], acc[mi][ni], 0, 0, 0);
    }
    __syncthreads();
    buf ^= 1;
  }

  if (EPI == 0) {
    float* C = (float*)Cv + b * cstride;
    #pragma unroll
    for (int mi = 0; mi < 8; ++mi) {
      int r = m0 + wm * 128 + mi * 16 + lk * 4;
      #pragma unroll
      for (int ni = 0; ni < 4; ++ni) {
        int c = n0 + wn * 64 + ni * 16 + lr;
        #pragma unroll
        for (int jj = 0; jj < 4; ++jj)
          C[(size_t)(r + jj) * ldc + c] = acc[mi][ni][jj];
      }
    }
  } else {
    // Each wave's 64 columns = one softmax group (head h, l=0..63).
    __hip_bfloat16* C = (__hip_bfloat16*)Cv + b * cstride;
    #pragma unroll
    for (int mi = 0; mi < 8; ++mi) {
      #pragma unroll
      for (int jj = 0; jj < 4; ++jj) {
        float mx = -3.0e38f;
        #pragma unroll
        for (int ni = 0; ni < 4; ++ni) mx = fmaxf(mx, acc[mi][ni][jj]);
        mx = fmaxf(mx, __shfl_xor(mx, 1));
        mx = fmaxf(mx, __shfl_xor(mx, 2));
        mx = fmaxf(mx, __shfl_xor(mx, 4));
        mx = fmaxf(mx, __shfl_xor(mx, 8));
        float e[4];
        float s = 0.f;
        #pragma unroll
        for (int ni = 0; ni < 4; ++ni) { e[ni] = __expf(acc[mi][ni][jj] - mx); s += e[ni]; }
        s += __shfl_xor(s, 1);
        s += __shfl_xor(s, 2);
        s += __shfl_xor(s, 4);
        s += __shfl_xor(s, 8);
        float inv = 1.0f / s;
        int r = m0 + wm * 128 + mi * 16 + lk * 4 + jj;
        #pragma unroll
        for (int ni = 0; ni < 4; ++ni)
          C[(size_t)r * ldc + n0 + wn * 64 + ni * 16 + lr] = __float2bfloat16(e[ni] * inv);
      }
    }
  }
}

// ---------------- kv projection, split-K=8: kvp[ks][256][2048] fp32 partials ----------------
// Stacked rows (b*64+t, t<64). 128x128 tile, BK=32, 4 waves, 4 K-iters/block, grid (2,16,8).
__global__ __launch_bounds__(256)
void gemm_kv(const __hip_bfloat16* __restrict__ A, const __hip_bfloat16* __restrict__ Bt,
             float* __restrict__ kvp) {
  __shared__ __align__(16) unsigned short As[128 * 32];
  __shared__ __align__(16) unsigned short Bs[128 * 32];
  const int tid = threadIdx.x;
  const int lane = tid & 63;
  const int w = tid >> 6;
  const int wm = w >> 1, wn = w & 1;
  const int lr = lane & 15, lk = lane >> 4;
  const int m0 = blockIdx.x * 128, n0 = blockIdx.y * 128;
  const int ks = blockIdx.z;
  const int K = 1024;

  f32x4 acc[4][4] = {};
  const int r0 = tid >> 2;
  const int c8 = (tid & 3) * 8;

  auto xrow = [&](int rg) { return (size_t)(rg >> 6) * 4096 + (rg & 63); };

  for (int ki = 0; ki < 4; ++ki) {
    int kt = ks * 128 + ki * 32;
    __syncthreads();
    gll16(A + xrow(m0 + r0) * K + kt + c8,      (char*)As + (w * 64) * 16);
    gll16(Bt + (size_t)(n0 + r0) * K + kt + c8, (char*)Bs + (w * 64) * 16);
    gll16(A + xrow(m0 + 64 + r0) * K + kt + c8,      (char*)As + (256 + w * 64) * 16);
    gll16(Bt + (size_t)(n0 + 64 + r0) * K + kt + c8, (char*)Bs + (256 + w * 64) * 16);
    __syncthreads();

    bf16x8 af[4], bf[4];
    #pragma unroll
    for (int mi = 0; mi < 4; ++mi)
      af[mi] = *(const bf16x8*)&As[(wm * 64 + mi * 16 + lr) * 32 + lk * 8];
    #pragma unroll
    for (int ni = 0; ni < 4; ++ni)
      bf[ni] = *(const bf16x8*)&Bs[(wn * 64 + ni * 16 + lr) * 32 + lk * 8];
    #pragma unroll
    for (int mi = 0; mi < 4; ++mi)
      #pragma unroll
      for (int ni = 0; ni < 4; ++ni)
        acc[mi][ni] = __builtin_amdgcn_mfma_f32_16x16x32_bf16(af[mi], bf[ni], acc[mi][ni], 0, 0, 0);
  }

  float* C = kvp + (size_t)ks * 256 * 2048;
  #pragma unroll
  for (int mi = 0; mi < 4; ++mi) {
    int r = m0 + wm * 64 + mi * 16 + lk * 4;
    #pragma unroll
    for (int ni = 0; ni < 4; ++ni) {
      int c = n0 + wn * 64 + ni * 16 + lr;
      #pragma unroll
      for (int jj = 0; jj < 4; ++jj)
        C[(size_t)(r + jj) * 2048 + c] = acc[mi][ni][jj];
    }
  }
}

// ---------------- attn (split-K sum + RoPE) + MFMA Mt build, merged: grid (4ct,16h,4b) -------
// WpT slice staged via gll16 FIRST (lands under attention compute). Attention redone per
// ct-block (cheap); ao written to LDS bf16 with ^(row&7) swizzle (plain ds_write).
// Mt_slice[256c][64l] = WpT_slice[256c][64d] @ ao[64l][64d]^T  via 16x16x32 MFMA.
__global__ __launch_bounds__(256)
void attn_mt(const float* __restrict__ kvp, const float* __restrict__ lq,
             const __hip_bfloat16* __restrict__ WpT, __hip_bfloat16* __restrict__ Mt) {
  const int ct = blockIdx.x, h = blockIdx.y, b = blockIdx.z;
  __shared__ float Ks[64][64];
  __shared__ float Vs[64][64];
  __shared__ float S[64][65];   // S[l][t]
  __shared__ float Pt[64][65];  // Pt[t][l]
  __shared__ __align__(16) unsigned short SW[256 * 64];   // WpT slice [256c][64d], swizzled
  __shared__ __align__(16) unsigned short SAo[64 * 64];   // ao bf16 [64l][64d], swizzled
  const int tid = threadIdx.x;
  const int lane = tid & 63;
  const int w = tid >> 6;
  const int lr = lane & 15, lk = lane >> 4;

  // stage WpT slice early — overlaps the whole attention phase
  #pragma unroll
  for (int j = 0; j < 8; ++j) {
    int c2 = j * 256 + tid;
    int row = c2 >> 3, slot = c2 & 7;
    int gch = slot ^ (row & 7);
    gll16(WpT + (size_t)(ct * 256 + row) * 1024 + h * 64 + gch * 8, (char*)SW + c2 * 16);
  }

  // ---- K/V: sum 8 split-K partials + RoPE on K ----
  {
    int r = tid >> 4;            // 0..15
    int c4 = (tid & 15) * 4;     // head-dim col (pairs i0=c4/2, i0+1)
    int i0 = c4 >> 1;
    float inv0 = exp2f(-13.287712379549449f * ((float)i0 * (1.0f / 32.0f)));
    float inv1 = exp2f(-13.287712379549449f * ((float)(i0 + 1) * (1.0f / 32.0f)));
    #pragma unroll
    for (int j = 0; j < 4; ++j) {
      int row = j * 16 + r;      // t
      float4 kf = make_float4(0.f, 0.f, 0.f, 0.f);
      float4 vf = make_float4(0.f, 0.f, 0.f, 0.f);
      #pragma unroll
      for (int ks = 0; ks < 8; ++ks) {
        const float* base = kvp + ((size_t)ks * 256 + b * 64 + row) * 2048 + h * 64;
        float4 kp = *(const float4*)(base + c4);
        float4 vp = *(const float4*)(base + 1024 + c4);
        kf.x += kp.x; kf.y += kp.y; kf.z += kp.z; kf.w += kp.w;
        vf.x += vp.x; vf.y += vp.y; vf.z += vp.z; vf.w += vp.w;
      }
      float a0 = (float)row * inv0, a1 = (float)row * inv1;
      float s0 = sinf(a0), c0 = cosf(a0), s1 = sinf(a1), c1 = cosf(a1);
      *(float4*)&Ks[row][c4] = make_float4(kf.x * c0 - kf.y * s0, kf.x * s0 + kf.y * c0,
                                           kf.z * c1 - kf.w * s1, kf.z * s1 + kf.w * c1);
      *(float4*)&Vs[row][c4] = vf;
    }
  }
  __syncthreads();

  // ---- scores: thread = (l = lane, t-chunk = wave) ----
  {
    const int l = tid & 63;
    float q[64];
    const float4* lq4 = (const float4*)(lq + ((size_t)l * 16 + h) * 64);
    #pragma unroll
    for (int i = 0; i < 16; ++i) {
      float4 f = lq4[i];
      q[4 * i] = f.x; q[4 * i + 1] = f.y; q[4 * i + 2] = f.z; q[4 * i + 3] = f.w;
    }
    #pragma unroll
    for (int tl = 0; tl < 16; ++tl) {
      int t = w * 16 + tl;
      float a = 0.f;
      #pragma unroll
      for (int d4 = 0; d4 < 16; ++d4) {
        float4 kf = *(const float4*)&Ks[t][d4 * 4];
        a += q[4 * d4] * kf.x + q[4 * d4 + 1] * kf.y + q[4 * d4 + 2] * kf.z + q[4 * d4 + 3] * kf.w;
      }
      S[l][t] = a * 0.125f;
    }
  }
  __syncthreads();

  // ---- softmax: thread = (l = tid>>2, c = tid&3), causal t<=l ----
  {
    const int l = tid >> 2, c = tid & 3;
    float sv[16];
    float mx = -3.0e38f;
    #pragma unroll
    for (int i = 0; i < 16; ++i) {
      int t = c * 16 + i;
      sv[i] = S[l][t];
      if (t <= l) mx = fmaxf(mx, sv[i]);
    }
    mx = fmaxf(mx, __shfl_xor(mx, 1));
    mx = fmaxf(mx, __shfl_xor(mx, 2));
    float sum = 0.f;
    float e[16];
    #pragma unroll
    for (int i = 0; i < 16; ++i) {
      int t = c * 16 + i;
      e[i] = (t <= l) ? __expf(sv[i] - mx) : 0.f;
      sum += e[i];
    }
    sum += __shfl_xor(sum, 1);
    sum += __shfl_xor(sum, 2);
    float inv = 1.0f / sum;
    #pragma unroll
    for (int i = 0; i < 16; ++i) Pt[c * 16 + i][l] = e[i] * inv;
  }
  __syncthreads();

  // ---- PV: thread = (l = lane, d-chunk = wave); ao -> SAo bf16 swizzled ----
  {
    const int l = tid & 63;
    float o[16];
    #pragma unroll
    for (int i = 0; i < 16; ++i) o[i] = 0.f;
    for (int t = 0; t < 64; ++t) {
      float p = Pt[t][l];
      #pragma unroll
      for (int d4 = 0; d4 < 4; ++d4) {
        float4 vf = *(const float4*)&Vs[t][w * 16 + d4 * 4];
        o[4 * d4]     += p * vf.x;
        o[4 * d4 + 1] += p * vf.y;
        o[4 * d4 + 2] += p * vf.z;
        o[4 * d4 + 3] += p * vf.w;
      }
    }
    union { __hip_bfloat16 hh[8]; bf16x8 v; } p0, p1;
    #pragma unroll
    for (int i = 0; i < 8; ++i) { p0.hh[i] = __float2bfloat16(o[i]); p1.hh[i] = __float2bfloat16(o[8 + i]); }
    // logical d-chunks 2w, 2w+1 of row l at physical chunk ^ (l&7)
    *(bf16x8*)&SAo[l * 64 + ((2 * w) ^ (l & 7)) * 8]     = p0.v;
    *(bf16x8*)&SAo[l * 64 + ((2 * w + 1) ^ (l & 7)) * 8] = p1.v;
  }
  __syncthreads();  // drains SAo ds_writes AND SW gll16 (vmcnt)

  // ---- MFMA: Mt_slice = SW @ SAo^T ----
  f32x4 acc[4][4] = {};
  bf16x8 bfr[2][4];
  #pragma unroll
  for (int kk = 0; kk < 2; ++kk)
    #pragma unroll
    for (int ni = 0; ni < 4; ++ni) {
      int row = ni * 16 + lr;
      int ch = (kk * 4 + lk) ^ (row & 7);
      bfr[kk][ni] = *(const bf16x8*)&SAo[row * 64 + ch * 8];
    }
  #pragma unroll
  for (int mi = 0; mi < 4; ++mi) {
    int row = w * 64 + mi * 16 + lr;
    int ch0 = lk ^ (row & 7);
    int ch1 = (4 + lk) ^ (row & 7);
    bf16x8 a0 = *(const bf16x8*)&SW[row * 64 + ch0 * 8];
    bf16x8 a1 = *(const bf16x8*)&SW[row * 64 + ch1 * 8];
    #pragma unroll
    for (int ni = 0; ni < 4; ++ni)
      acc[mi][ni] = __builtin_amdgcn_mfma_f32_16x16x32_bf16(a0, bfr[0][ni], acc[mi][ni], 0, 0, 0);
    #pragma unroll
    for (int ni = 0; ni < 4; ++ni)
      acc[mi][ni] = __builtin_amdgcn_mfma_f32_16x16x32_bf16(a1, bfr[1][ni], acc[mi][ni], 0, 0, 0);
  }

  // C-layout: row(c) = ct*256 + w*64 + mi*16 + lk*4 + jj, col(l) = ni*16 + lr
  #pragma unroll
  for (int mi = 0; mi < 4; ++mi) {
    int c = ct * 256 + w * 64 + mi * 16 + lk * 4;
    #pragma unroll
    for (int ni = 0; ni < 4; ++ni) {
      int l = ni * 16 + lr;
      #pragma unroll
      for (int jj = 0; jj < 4; ++jj)
        Mt[((size_t)b * 1024 + c + jj) * 1024 + h * 64 + l] = __float2bfloat16(acc[mi][ni][jj]);
    }
  }
}

extern "C" void kernel_launch(void* const* d_in, const int* in_sizes, int n_in,
                              void* d_out, int out_size, void* d_ws, size_t ws_size,
                              hipStream_t stream) {
  const float* x  = (const float*)d_in[0];
  const float* lq = (const float*)d_in[1];
  const float* Wk = (const float*)d_in[2];
  const float* Wv = (const float*)d_in[3];
  const float* Wg = (const float*)d_in[4];
  const float* Wp = (const float*)d_in[5];
  float* out = (float*)d_out;

  // workspace layout (bytes)
  char* w = (char*)d_ws;
  __hip_bfloat16* xb   = (__hip_bfloat16*)(w);              // 33,554,432
  __hip_bfloat16* G    = (__hip_bfloat16*)(w + 33554432);   // 33,554,432
  __hip_bfloat16* WgT  = (__hip_bfloat16*)(w + 67108864);   // 2,097,152
  __hip_bfloat16* WkvT = (__hip_bfloat16*)(w + 69206016);   // 4,194,304
  __hip_bfloat16* WpT  = (__hip_bfloat16*)(w + 73400320);   // 2,097,152
  __hip_bfloat16* Mt   = (__hip_bfloat16*)(w + 75497472);   // 8,388,608
  // total 83,886,080 B
  // kv partials live in d_out (16MB of its 64MB), consumed by attn_mt before
  // the final GEMM overwrites all of d_out. Deterministic.
  float* kvp = out;

  // x->bf16 + 4 weight transposes, one launch
  prep_kernel<<<6144, 256, 0, stream>>>(x, xb, Wg, Wk, Wv, Wp,
                                        WgT, WkvT, WkvT + 1024 * 1024, WpT);

  // gates: G = softmax_groups(x @ Wg), bf16 [16384,1024] (proven 2-phase)
  gemm256<1><<<dim3(64, 4, 1), 512, 0, stream>>>(xb, WgT, G, 1024, 1024, 0LL, 0LL, 0LL);

  // k,v split-K partials: kvp[8][256][2048] fp32 (stacked rows b*64+t)
  gemm_kv<<<dim3(2, 16, 8), 256, 0, stream>>>(xb, WkvT, kvp);

  // attention (+partial sum +RoPE) + MFMA Mt build, merged
  attn_mt<<<dim3(4, 16, 4), 256, 0, stream>>>(kvp, lq, WpT, Mt);

  // out[b] = G[b] @ Mt[b]^T (fp32 out, overwrites kvp scratch) (proven 2-phase)
  gemm256<0><<<dim3(16, 4, 4), 512, 0, stream>>>(G, Mt, out, 1024, 1024,
                                                 4096LL * 1024, 1024LL * 1024, 4096LL * 1024);
}